// Round 9
// baseline (194.031 us; speedup 1.0000x reference)
//
#include <hip/hip_runtime.h>

typedef _Float16 f16;
typedef __attribute__((ext_vector_type(4))) _Float16 f16x4;
typedef __attribute__((ext_vector_type(8))) _Float16 f16x8;
typedef __attribute__((ext_vector_type(4))) float f32x4;

#define MFMA16(a, b, c) __builtin_amdgcn_mfma_f32_16x16x32_f16((a), (b), (c), 0, 0, 0)

__device__ __forceinline__ f16x8 cvt8(float4 a, float4 b) {
    f16x8 r;
    r[0] = (f16)a.x; r[1] = (f16)a.y; r[2] = (f16)a.z; r[3] = (f16)a.w;
    r[4] = (f16)b.x; r[5] = (f16)b.y; r[6] = (f16)b.z; r[7] = (f16)b.w;
    return r;
}

__device__ __forceinline__ f16x8 zero8() {
    f16x8 z;
#pragma unroll
    for (int q = 0; q < 8; ++q) z[q] = (f16)0.0f;
    return z;
}

// ---------------- pre-kernel: fp16 weights + fused bias constants into ws ----
__global__ void prep_kernel(const float* __restrict__ w_ih, const float* __restrict__ w_hh,
                            const float* __restrict__ b_ih, const float* __restrict__ b_hh,
                            const float* __restrict__ b_iah, const float* __restrict__ b_oah,
                            const float* __restrict__ W_in, const float* __restrict__ bias_in,
                            const float* __restrict__ W_out, const float* __restrict__ bias_out,
                            f16* __restrict__ Wc, f16* __restrict__ Whh, f16* __restrict__ Wih,
                            float* __restrict__ cstA, float* __restrict__ cstB,
                            float* __restrict__ biasc) {
    const int gid = blockIdx.x * 256 + threadIdx.x;
    const int gstride = gridDim.x * 256;
    for (int i = gid; i < 8192; i += gstride)
        Wc[i] = (f16)(i < 4096 ? W_in[i] : W_out[i - 4096]);
    for (int i = gid; i < 12288; i += gstride) Whh[i] = (f16)w_hh[i];   // [192][64]
    for (int i = gid; i < 24576; i += gstride) Wih[i] = (f16)w_ih[i];   // [192][128]
    for (int job = gid; job < 768; job += gstride) {
        const int g = job >> 2, q = job & 3;
        float s = (q == 0) ? b_ih[g] : 0.0f;
        const float* wr = w_ih + g * 128 + q * 32;
        for (int i = 0; i < 32; ++i)
            s += wr[i] * ((q * 32 + i < 64) ? b_iah[q * 32 + i] : b_oah[q * 32 + i - 64]);
        atomicAdd(&cstA[g], s);
    }
    for (int g = gid; g < 192; g += gstride) cstB[g] = b_hh[g];
    for (int j = gid; j < 128; j += gstride) biasc[j] = (j < 64) ? bias_in[j] : bias_out[j - 64];
}

__global__ void zero_kernel(float* __restrict__ cstA) {
    if (threadIdx.x < 192) cstA[threadIdx.x] = 0.0f;
}

// ---- Phase 2 worker: NT row-tiles, all 4 col-tiles of this wave's half. ----
// 1x A reads (disjoint rows per wave), B-frags from LDS hT (live, read-only),
// results packed f16 in registers. Fully static prefetch slot parity.
template<int NT>
__device__ __forceinline__ void phase2_run(const float* const rp[4], const f16* hTb,
                                           const int lg, f16x4 pk[4][4]) {
    float4 p[2][2];
    p[0][0] = *(const float4*)(rp[0] + lg * 8);
    p[0][1] = *(const float4*)(rp[0] + lg * 8 + 4);
    p[1][0] = *(const float4*)(rp[0] + 32 + lg * 8);
    p[1][1] = *(const float4*)(rp[0] + 32 + lg * 8 + 4);
    f32x4 acc[4];
#pragma unroll
    for (int s = 0; s < NT * 7; ++s) {
        const int tt = s / 7, k = s % 7;
        float4 q0 = p[s & 1][0], q1 = p[s & 1][1];
        const int ns = s + 2;
        if (ns < NT * 7) {                       // prefetch 2 steps ahead
            const int nt_ = ns / 7, nk = ns % 7;
            const float* ap = rp[nt_] + (nk < 6 ? nk * 32 + lg * 8 : 192);
            p[s & 1][0] = *(const float4*)ap;
            p[s & 1][1] = *(const float4*)(ap + 4);
        }
        if (k == 0) {
#pragma unroll
            for (int c = 0; c < 4; ++c) acc[c] = (f32x4){0.f, 0.f, 0.f, 0.f};
        }
        f16x8 af = (k == 6 && lg != 0) ? zero8() : cvt8(q0, q1);
        const int koffB = (k == 6) ? 192 : k * 32 + lg * 8;  // lg>0@k6: clamped, x0
#pragma unroll
        for (int c = 0; c < 4; ++c) {
            const f16x8 bf = *(const f16x8*)(hTb + c * 3200 + koffB);
            acc[c] = MFMA16(af, bf, acc[c]);
        }
        if (k == 6) {
#pragma unroll
            for (int c = 0; c < 4; ++c) {
                f16x4 t;
                t[0] = (f16)acc[c][0]; t[1] = (f16)acc[c][1];
                t[2] = (f16)acc[c][2]; t[3] = (f16)acc[c][3];
                pk[tt][c] = t;
            }
        }
    }
}

// ---------------- fused main kernel: one WG (512 thr) per batch b ------------
// LDS 60800 B, aliased:
//   P1/P2: hT  [128][200] f16 (51200)  h_cat^T  (live through ALL of phase 2)
//   P3:    inp [200][152] f16 (60800)  (written from registers after barrier)
// Phase 2: wave = (half hf, quarter q); rows {q,q+4,q+8,q+12}; all 64 cols of
// half; A read exactly ONCE grid-wide; no LDS writes, no barriers.
__global__ __launch_bounds__(512, 2) void gru_fused(
    const float* __restrict__ A, const float* __restrict__ hidden,
    const f16* __restrict__ Wc, const f16* __restrict__ Whh, const f16* __restrict__ Wih,
    const float* __restrict__ cstA, const float* __restrict__ cstB,
    const float* __restrict__ biasc, float* __restrict__ out) {
    __shared__ __align__(16) char lds_raw[60800];
    f16* hT  = (f16*)lds_raw;   // [128][200]
    f16* inp = (f16*)lds_raw;   // [200][152] alias

    const int b = blockIdx.x;
    const float* Ab = A + (size_t)b * 80000;      // [400][200]
    const float* hb = hidden + (size_t)b * 12800; // [200][64]
    float* ob = out + (size_t)b * 12800;

    const int tid = threadIdx.x;
    const int w   = tid >> 6;
    const int l   = tid & 63;
    const int l15 = l & 15;
    const int lg  = l >> 4;

    // ---- Phase 1: hT[j][m] = f16(hidden[m,:]@Wc[j,:] + biasc[j]) ----
    for (int mt = w; mt < 13; mt += 8) {
        const int m  = mt * 16 + l15;
        const int mc = m < 200 ? m : 199;
        const float* hrow = hb + mc * 64;
        float4 r0 = *(const float4*)(hrow + lg * 8);
        float4 r1 = *(const float4*)(hrow + lg * 8 + 4);
        float4 r2 = *(const float4*)(hrow + 32 + lg * 8);
        float4 r3 = *(const float4*)(hrow + 32 + lg * 8 + 4);
        f16x8 a0 = cvt8(r0, r1), a1 = cvt8(r2, r3);
        const int m0 = mt * 16 + lg * 4;
#pragma unroll
        for (int jt = 0; jt < 8; ++jt) {
            const int j = jt * 16 + l15;
            f32x4 acc = {0.f, 0.f, 0.f, 0.f};
            acc = MFMA16(a0, *(const f16x8*)(Wc + j * 64 + lg * 8), acc);
            acc = MFMA16(a1, *(const f16x8*)(Wc + j * 64 + 32 + lg * 8), acc);
            const float bc = biasc[j];
            if (m0 < 200) {
                f16x4 pkk;
                pkk[0] = (f16)(acc[0] + bc); pkk[1] = (f16)(acc[1] + bc);
                pkk[2] = (f16)(acc[2] + bc); pkk[3] = (f16)(acc[3] + bc);
                *(f16x4*)(hT + j * 200 + m0) = pkk;
            }
        }
    }
    __syncthreads();

    // ---- Phase 2 ----
    const int hf = w >> 2;   // half: output cols [hf*64, hf*64+64)
    const int q  = w & 3;    // quarter: row-tiles q, q+4, q+8, (q+12)
    const float* rp[4];
#pragma unroll
    for (int ti = 0; ti < 4; ++ti) {
        const int t = q + 4 * ti;
        int row = t * 16 + l15;
        if (row > 199) row = 199;
        rp[ti] = Ab + (size_t)(hf * 200 + row) * 200;
    }
    const f16* hTb = hT + (hf * 64 + l15) * 200;

    f16x4 pk[4][4];
    if (q == 0) phase2_run<4>(rp, hTb, lg, pk);
    else        phase2_run<3>(rp, hTb, lg, pk);
    __syncthreads();   // all waves done READING hT -> inp may overwrite

    const int NT = (q == 0) ? 4 : 3;
#pragma unroll
    for (int ti = 0; ti < 4; ++ti) {
        if (ti < NT) {
#pragma unroll
            for (int c = 0; c < 4; ++c) {
#pragma unroll
                for (int r = 0; r < 4; ++r) {
                    const int n = (q + 4 * ti) * 16 + lg * 4 + r;
                    if (n < 200) inp[n * 152 + hf * 64 + c * 16 + l15] = pk[ti][c][r];
                }
            }
        }
    }
    __syncthreads();

    // ---- Phase 3: gi = inputs@w_ih^T, gh = hidden@w_hh^T, gates, store ----
    const int c    = w & 3;
    const int wm2  = w >> 2;
    const int hcol = c * 16 + l15;
    f16x8 Wf0[4], Wf1[4], Wf2[4];
#pragma unroll
    for (int k = 0; k < 4; ++k) {
        Wf0[k] = *(const f16x8*)(Wih + (hcol      ) * 128 + k * 32 + lg * 8);
        Wf1[k] = *(const f16x8*)(Wih + (64  + hcol) * 128 + k * 32 + lg * 8);
        Wf2[k] = *(const f16x8*)(Wih + (128 + hcol) * 128 + k * 32 + lg * 8);
    }
    f16x8 Hf0[2], Hf1[2], Hf2[2];
#pragma unroll
    for (int k = 0; k < 2; ++k) {
        Hf0[k] = *(const f16x8*)(Whh + (hcol      ) * 64 + k * 32 + lg * 8);
        Hf1[k] = *(const f16x8*)(Whh + (64  + hcol) * 64 + k * 32 + lg * 8);
        Hf2[k] = *(const f16x8*)(Whh + (128 + hcol) * 64 + k * 32 + lg * 8);
    }
    const float cAr = cstA[hcol], cAi = cstA[64 + hcol], cAn = cstA[128 + hcol];
    const float cBr = cstB[hcol], cBi = cstB[64 + hcol], cBn = cstB[128 + hcol];

    for (int t = wm2; t < 13; t += 2) {
        const int n  = t * 16 + l15;
        const int nc = n < 200 ? n : 199;
        f32x4 gir = {0.f,0.f,0.f,0.f}, gii = {0.f,0.f,0.f,0.f}, gin = {0.f,0.f,0.f,0.f};
        f32x4 ghr = {0.f,0.f,0.f,0.f}, ghi = {0.f,0.f,0.f,0.f}, ghn = {0.f,0.f,0.f,0.f};
#pragma unroll
        for (int k = 0; k < 2; ++k) {          // gh first: global loads issue early
            const int h = k * 32 + lg * 8;
            float4 r0 = *(const float4*)(hb + nc * 64 + h);
            float4 r1 = *(const float4*)(hb + nc * 64 + h + 4);
            f16x8 a = cvt8(r0, r1);
            ghr = MFMA16(a, Hf0[k], ghr);
            ghi = MFMA16(a, Hf1[k], ghi);
            ghn = MFMA16(a, Hf2[k], ghn);
        }
#pragma unroll
        for (int k = 0; k < 4; ++k) {          // gi: K = 128, inp in LDS
            f16x8 a = *(const f16x8*)(inp + nc * 152 + k * 32 + lg * 8);
            gir = MFMA16(a, Wf0[k], gir);
            gii = MFMA16(a, Wf1[k], gii);
            gin = MFMA16(a, Wf2[k], gin);
        }
#pragma unroll
        for (int r = 0; r < 4; ++r) {
            const int row = t * 16 + lg * 4 + r;
            if (row < 200) {
                const float hv = hb[row * 64 + hcol];
                const float xr = gir[r] + ghr[r] + cAr + cBr;
                const float xi = gii[r] + ghi[r] + cAi + cBi;
                const float rg2 = 1.0f / (1.0f + __expf(-xr));
                const float ig = 1.0f / (1.0f + __expf(-xi));
                const float xn = gin[r] + cAn + rg2 * (ghn[r] + cBn);
                const float e2 = __expf(2.0f * xn);
                const float ng = 1.0f - 2.0f / (e2 + 1.0f);
                ob[row * 64 + hcol] = hv + ig * (ng - hv);
            }
        }
    }
}

extern "C" void kernel_launch(void* const* d_in, const int* in_sizes, int n_in,
                              void* d_out, int out_size, void* d_ws, size_t ws_size,
                              hipStream_t stream) {
    const float* A        = (const float*)d_in[0];
    const float* hidden   = (const float*)d_in[1];
    const float* w_ih     = (const float*)d_in[2];
    const float* w_hh     = (const float*)d_in[3];
    const float* b_ih     = (const float*)d_in[4];
    const float* b_hh     = (const float*)d_in[5];
    const float* b_iah    = (const float*)d_in[6];
    const float* b_oah    = (const float*)d_in[7];
    const float* W_in     = (const float*)d_in[8];
    const float* bias_in  = (const float*)d_in[9];
    const float* W_out    = (const float*)d_in[10];
    const float* bias_out = (const float*)d_in[11];
    float* out = (float*)d_out;

    char* wsb = (char*)d_ws;
    f16* Wc      = (f16*)wsb;            // 8192 f16
    f16* Whh     = Wc + 8192;            // 12288 f16
    f16* Wih     = Whh + 12288;          // 24576 f16
    float* cstA  = (float*)(wsb + 90112);
    float* cstB  = cstA + 192;
    float* biasc = cstB + 192;

    zero_kernel<<<dim3(1), dim3(256), 0, stream>>>(cstA);
    prep_kernel<<<dim3(64), dim3(256), 0, stream>>>(
        w_ih, w_hh, b_ih, b_hh, b_iah, b_oah, W_in, bias_in, W_out, bias_out,
        Wc, Whh, Wih, cstA, cstB, biasc);
    gru_fused<<<dim3(1024), dim3(512), 0, stream>>>(
        A, hidden, Wc, Whh, Wih, cstA, cstB, biasc, out);
}